// Round 1
// baseline (5940.404 us; speedup 1.0000x reference)
//
#include <hip/hip_runtime.h>
#include <cstdint>
#include <cstddef>

#define N_ROWS 131072   // B*T
#define K_CB   1024
#define D_DIM  256
#define ND_TOT 33554432ull   // D*N
#define NK_TOT 134217728ull  // N*K

static __device__ __forceinline__ float omd() { return (float)(1.0 - 0.99); }  // match python 1-DECAY

// ---------------- xsq: per-row squared norm of flat (stored [D][N]) ----------
__global__ __launch_bounds__(256) void xsq_k(const float* __restrict__ in, float* __restrict__ xsq) {
  int n = blockIdx.x * 256 + threadIdx.x;
  float s = 0.f;
#pragma unroll 8
  for (int d = 0; d < D_DIM; ++d) {
    float v = in[(size_t)d * N_ROWS + n];
    s += v * v;
  }
  xsq[n] = s;
}

// ---------------- esq: per-code squared norm (emb [K][D] row-major) ----------
__global__ __launch_bounds__(256) void esq_k(const float* __restrict__ emb, float* __restrict__ esq) {
  int k = blockIdx.x * 4 + (threadIdx.x >> 6);
  int lane = threadIdx.x & 63;
  const float* er = emb + (size_t)k * D_DIM;
  float s = 0.f;
#pragma unroll
  for (int t = 0; t < 4; ++t) { float v = er[t * 64 + lane]; s += v * v; }
  for (int off = 32; off; off >>= 1) s += __shfl_down(s, off);
  if (lane == 0) esq[k] = s;
}

// ---------------- fp32 GEMM + distance epilogue -----------------------------
// A = flat [N,D] stored as in[d*N+n] (i.e. A^T row-major). B = emb [K,D].
// dist[n,k] = xsq[n] + esq[k] - 2 * sum_d A[n,d]*B[k,d]
__global__ __launch_bounds__(256) void gemm_dist_k(
    const float* __restrict__ in, const float* __restrict__ emb,
    const float* __restrict__ xsq, const float* __restrict__ esq,
    float* __restrict__ dist) {
  __shared__ float As[8][128];
  __shared__ float Bs[8][132];  // +4 pad
  const int tid = threadIdx.x;
  const int n0 = blockIdx.x * 128, k0 = blockIdx.y * 128;
  const int tm = tid >> 4, tn = tid & 15;
  const int a_dk = tid >> 5, a_nn = (tid & 31) << 2;
  const int b_kk = tid >> 1, b_dk = (tid & 1) << 2;
  float acc[8][8] = {};
  for (int d0 = 0; d0 < D_DIM; d0 += 8) {
    float4 av = *(const float4*)&in[(size_t)(d0 + a_dk) * N_ROWS + n0 + a_nn];
    float4 bv = *(const float4*)&emb[(size_t)(k0 + b_kk) * D_DIM + d0 + b_dk];
    __syncthreads();
    *(float4*)&As[a_dk][a_nn] = av;
    Bs[b_dk + 0][b_kk] = bv.x;
    Bs[b_dk + 1][b_kk] = bv.y;
    Bs[b_dk + 2][b_kk] = bv.z;
    Bs[b_dk + 3][b_kk] = bv.w;
    __syncthreads();
#pragma unroll
    for (int dk = 0; dk < 8; ++dk) {
      float a[8], b[8];
      *(float4*)&a[0] = *(const float4*)&As[dk][tm * 8];
      *(float4*)&a[4] = *(const float4*)&As[dk][tm * 8 + 4];
      *(float4*)&b[0] = *(const float4*)&Bs[dk][tn * 8];
      *(float4*)&b[4] = *(const float4*)&Bs[dk][tn * 8 + 4];
#pragma unroll
      for (int i = 0; i < 8; ++i)
#pragma unroll
        for (int j = 0; j < 8; ++j)
          acc[i][j] += a[i] * b[j];
    }
  }
  float es[8];
#pragma unroll
  for (int j = 0; j < 8; ++j) es[j] = esq[k0 + tn * 8 + j];
#pragma unroll
  for (int i = 0; i < 8; ++i) {
    int n = n0 + tm * 8 + i;
    float xs = xsq[n];
    float4 o0, o1;
    o0.x = xs + es[0] - 2.f * acc[i][0];
    o0.y = xs + es[1] - 2.f * acc[i][1];
    o0.z = xs + es[2] - 2.f * acc[i][2];
    o0.w = xs + es[3] - 2.f * acc[i][3];
    o1.x = xs + es[4] - 2.f * acc[i][4];
    o1.y = xs + es[5] - 2.f * acc[i][5];
    o1.z = xs + es[6] - 2.f * acc[i][6];
    o1.w = xs + es[7] - 2.f * acc[i][7];
    *(float4*)&dist[(size_t)n * K_CB + k0 + tn * 8] = o0;
    *(float4*)&dist[(size_t)n * K_CB + k0 + tn * 8 + 4] = o1;
  }
}

// ---------------- argmin per row (first-occurrence tie-break) ---------------
__global__ __launch_bounds__(256) void argmin_k(const float* __restrict__ dist, int* __restrict__ idx) {
  int row = blockIdx.x * 4 + (threadIdx.x >> 6);
  int lane = threadIdx.x & 63;
  const float* dr = dist + (size_t)row * K_CB;
  float mv = INFINITY;
  int mi = 0x7fffffff;
#pragma unroll
  for (int t = 0; t < 16; ++t) {
    int k = t * 64 + lane;  // increasing k per lane -> first occurrence kept
    float v = dr[k];
    if (v < mv) { mv = v; mi = k; }
  }
  for (int off = 32; off; off >>= 1) {
    float ov = __shfl_down(mv, off);
    int oi = __shfl_down(mi, off);
    if (ov < mv || (ov == mv && oi < mi)) { mv = ov; mi = oi; }
  }
  if (lane == 0) idx[row] = mi;
}

// ---------------- one-hot scatter + float indices ---------------------------
__global__ __launch_bounds__(256) void scat_k(const int* __restrict__ idx,
                                              float* __restrict__ enc, float* __restrict__ idxf) {
  int n = blockIdx.x * 256 + threadIdx.x;
  int k = idx[n];
  enc[(size_t)n * K_CB + k] = 1.0f;
  idxf[n] = (float)k;
}

// ---------------- counts ----------------------------------------------------
__global__ __launch_bounds__(256) void counts_k(const int* __restrict__ idx, unsigned* __restrict__ counts) {
  int n = blockIdx.x * 256 + threadIdx.x;
  atomicAdd(&counts[idx[n]], 1u);
}

// ---------------- dw scatter-add --------------------------------------------
__global__ __launch_bounds__(256) void dw_k(const float* __restrict__ in,
                                            const int* __restrict__ idx, float* __restrict__ dw) {
  size_t i = (size_t)blockIdx.x * 256 + threadIdx.x;
  size_t stride = (size_t)gridDim.x * 256;
  for (; i < ND_TOT; i += stride) {
    int d = (int)(i >> 17);          // N = 2^17
    int n = (int)(i & (N_ROWS - 1));
    atomicAdd(&dw[(size_t)idx[n] * D_DIM + d], in[i]);
  }
}

// ---------------- new cluster sizes + perplexity ----------------------------
__global__ __launch_bounds__(1024) void newcs_k(const float* __restrict__ ema_cs,
                                                const unsigned* __restrict__ counts,
                                                float* __restrict__ out_ncs,
                                                float* __restrict__ out_perp) {
  __shared__ float s[1024];
  int k = threadIdx.x;
  float c = (float)counts[k];
  float raw = 0.99f * ema_cs[k] + omd() * c;
  s[k] = raw;
  __syncthreads();
  for (int off = 512; off; off >>= 1) { if (k < off) s[k] += s[k + off]; __syncthreads(); }
  float nsum = s[0];
  __syncthreads();
  out_ncs[k] = (raw + 1e-5f) / (nsum + (float)(1024 * 1e-5)) * nsum;
  float p = c * (1.0f / 131072.0f);
  float t = p * logf(p + 1e-10f);
  s[k] = t;
  __syncthreads();
  for (int off = 512; off; off >>= 1) { if (k < off) s[k] += s[k + off]; __syncthreads(); }
  if (k == 0) out_perp[0] = expf(-s[0]);
}

// ---------------- new ema_w + new embedding ---------------------------------
__global__ __launch_bounds__(256) void newemb_k(const float* __restrict__ ema_w,
                                                const float* __restrict__ dw,
                                                const float* __restrict__ ncs,
                                                float* __restrict__ out_nw,
                                                float* __restrict__ out_ne) {
  int i = blockIdx.x * 256 + threadIdx.x;
  int k = i >> 8;  // D=256
  float nw = 0.99f * ema_w[i] + omd() * dw[i];
  out_nw[i] = nw;
  out_ne[i] = nw / ncs[k];
}

// ---------------- quantize (gather) + ST output + latent loss ---------------
__global__ __launch_bounds__(256) void quant_k(const float* __restrict__ in,
                                               const int* __restrict__ idx,
                                               const float* __restrict__ ne,
                                               float* __restrict__ qout,
                                               float* __restrict__ lossacc) {
  float lacc = 0.f;
  size_t stride = (size_t)gridDim.x * 256;
  for (size_t i = (size_t)blockIdx.x * 256 + threadIdx.x; i < ND_TOT; i += stride) {
    int d = (int)(i >> 17);
    int n = (int)(i & (N_ROWS - 1));
    float x = in[i];
    float q = ne[(size_t)idx[n] * D_DIM + d];
    float dlt = q - x;
    qout[i] = x + dlt;   // straight-through, matches ref rounding
    lacc += dlt * dlt;
  }
  for (int off = 32; off; off >>= 1) lacc += __shfl_down(lacc, off);
  __shared__ float w4[4];
  if ((threadIdx.x & 63) == 0) w4[threadIdx.x >> 6] = lacc;
  __syncthreads();
  if (threadIdx.x == 0) atomicAdd(lossacc, w4[0] + w4[1] + w4[2] + w4[3]);
}

__global__ void fin_k(const float* __restrict__ lossacc, float* __restrict__ out_loss) {
  out_loss[0] = 0.25f * lossacc[0] * (1.0f / 33554432.0f);
}

extern "C" void kernel_launch(void* const* d_in, const int* in_sizes, int n_in,
                              void* d_out, int out_size, void* d_ws, size_t ws_size,
                              hipStream_t stream) {
  const float* in     = (const float*)d_in[0];  // [D,B,T] = [256, 64, 2048]
  const float* emb    = (const float*)d_in[1];  // [K,D]
  const float* ema_cs = (const float*)d_in[2];  // [K]
  const float* ema_w  = (const float*)d_in[3];  // [K,D]

  float* out = (float*)d_out;
  float* out_loss = out;                       // 1
  float* out_q    = out + 1;                   // 33554432
  float* out_perp = out + 33554433;            // 1
  float* out_enc  = out + 33554434;            // 134217728
  float* out_dist = out + 167772162;           // 134217728
  float* out_idx  = out + 301989890;           // 131072
  float* out_ncs  = out + 302120962;           // 1024
  float* out_nw   = out + 302121986;           // 262144
  float* out_ne   = out + 302384130;           // 262144

  char* w = (char*)d_ws;
  float*    dw      = (float*)(w);                 // K*D floats = 1 MiB
  unsigned* counts  = (unsigned*)(w + 1048576);    // 1024 u32
  float*    lossacc = (float*)(w + 1052672);       // 1 f32 (padded)
  float*    xsq     = (float*)(w + 1052928);       // N f32
  float*    esq     = (float*)(w + 1577216);       // K f32
  int*      idx     = (int*)(w + 1581312);         // N i32

  // zero accumulators (ws is NOT re-poisoned between replays -> must re-zero)
  hipMemsetAsync(d_ws, 0, 1052928, stream);
  // zero one-hot encodings output
  hipMemsetAsync(out_enc, 0, NK_TOT * 4, stream);

  xsq_k<<<N_ROWS / 256, 256, 0, stream>>>(in, xsq);
  esq_k<<<K_CB / 4, 256, 0, stream>>>(emb, esq);
  gemm_dist_k<<<dim3(N_ROWS / 128, K_CB / 128), 256, 0, stream>>>(in, emb, xsq, esq, out_dist);
  argmin_k<<<N_ROWS / 4, 256, 0, stream>>>(out_dist, idx);
  scat_k<<<N_ROWS / 256, 256, 0, stream>>>(idx, out_enc, out_idx);
  counts_k<<<N_ROWS / 256, 256, 0, stream>>>(idx, counts);
  dw_k<<<2048, 256, 0, stream>>>(in, idx, dw);
  newcs_k<<<1, 1024, 0, stream>>>(ema_cs, counts, out_ncs, out_perp);
  newemb_k<<<K_CB * D_DIM / 256, 256, 0, stream>>>(ema_w, dw, out_ncs, out_nw, out_ne);
  quant_k<<<2048, 256, 0, stream>>>(in, idx, out_ne, out_q, lossacc);
  fin_k<<<1, 1, 0, stream>>>(lossacc, out_loss);
}

// Round 2
// 2403.924 us; speedup vs baseline: 2.4711x; 2.4711x over previous
//
#include <hip/hip_runtime.h>
#include <cstdint>
#include <cstddef>

#define N_ROWS 131072   // B*T
#define K_CB   1024
#define D_DIM  256
#define ND_TOT 33554432ull   // D*N
#define NK_TOT 134217728ull  // N*K

static __device__ __forceinline__ float omd() { return (float)(1.0 - 0.99); }

// ---------------- xsq: per-row squared norm of flat (stored [D][N]) ----------
__global__ __launch_bounds__(256) void xsq_k(const float* __restrict__ in, float* __restrict__ xsq) {
  int n = blockIdx.x * 256 + threadIdx.x;
  float s = 0.f;
#pragma unroll 8
  for (int d = 0; d < D_DIM; ++d) {
    float v = in[(size_t)d * N_ROWS + n];
    s += v * v;
  }
  xsq[n] = s;
}

// ---------------- esq: per-code squared norm (emb [K][D] row-major) ----------
__global__ __launch_bounds__(256) void esq_k(const float* __restrict__ emb, float* __restrict__ esq) {
  int k = blockIdx.x * 4 + (threadIdx.x >> 6);
  int lane = threadIdx.x & 63;
  const float* er = emb + (size_t)k * D_DIM;
  float s = 0.f;
#pragma unroll
  for (int t = 0; t < 4; ++t) { float v = er[t * 64 + lane]; s += v * v; }
  for (int off = 32; off; off >>= 1) s += __shfl_down(s, off);
  if (lane == 0) esq[k] = s;
}

// ---------------- tiled transpose: in [D][N] -> flatT [N][D] ----------------
__global__ __launch_bounds__(256) void tr_k(const float* __restrict__ in, float* __restrict__ flatT) {
  __shared__ float tile[64][65];
  int n0 = blockIdx.x * 64, d0 = blockIdx.y * 64;
  int lane = threadIdx.x & 63, grp = threadIdx.x >> 6;
#pragma unroll
  for (int r = 0; r < 16; ++r) {
    int dr = grp * 16 + r;
    tile[dr][lane] = in[(size_t)(d0 + dr) * N_ROWS + n0 + lane];
  }
  __syncthreads();
#pragma unroll
  for (int r = 0; r < 16; ++r) {
    int nr = grp * 16 + r;
    flatT[(size_t)(n0 + nr) * D_DIM + d0 + lane] = tile[lane][nr];
  }
}

// ---------------- fp32 GEMM + distance epilogue -----------------------------
__global__ __launch_bounds__(256) void gemm_dist_k(
    const float* __restrict__ in, const float* __restrict__ emb,
    const float* __restrict__ xsq, const float* __restrict__ esq,
    float* __restrict__ dist) {
  __shared__ float As[8][128];
  __shared__ float Bs[8][132];
  const int tid = threadIdx.x;
  const int n0 = blockIdx.x * 128, k0 = blockIdx.y * 128;
  const int tm = tid >> 4, tn = tid & 15;
  const int a_dk = tid >> 5, a_nn = (tid & 31) << 2;
  const int b_kk = tid >> 1, b_dk = (tid & 1) << 2;
  float acc[8][8] = {};
  for (int d0 = 0; d0 < D_DIM; d0 += 8) {
    float4 av = *(const float4*)&in[(size_t)(d0 + a_dk) * N_ROWS + n0 + a_nn];
    float4 bv = *(const float4*)&emb[(size_t)(k0 + b_kk) * D_DIM + d0 + b_dk];
    __syncthreads();
    *(float4*)&As[a_dk][a_nn] = av;
    Bs[b_dk + 0][b_kk] = bv.x;
    Bs[b_dk + 1][b_kk] = bv.y;
    Bs[b_dk + 2][b_kk] = bv.z;
    Bs[b_dk + 3][b_kk] = bv.w;
    __syncthreads();
#pragma unroll
    for (int dk = 0; dk < 8; ++dk) {
      float a[8], b[8];
      *(float4*)&a[0] = *(const float4*)&As[dk][tm * 8];
      *(float4*)&a[4] = *(const float4*)&As[dk][tm * 8 + 4];
      *(float4*)&b[0] = *(const float4*)&Bs[dk][tn * 8];
      *(float4*)&b[4] = *(const float4*)&Bs[dk][tn * 8 + 4];
#pragma unroll
      for (int i = 0; i < 8; ++i)
#pragma unroll
        for (int j = 0; j < 8; ++j)
          acc[i][j] += a[i] * b[j];
    }
  }
  float es[8];
#pragma unroll
  for (int j = 0; j < 8; ++j) es[j] = esq[k0 + tn * 8 + j];
#pragma unroll
  for (int i = 0; i < 8; ++i) {
    int n = n0 + tm * 8 + i;
    float xs = xsq[n];
    float4 o0, o1;
    o0.x = xs + es[0] - 2.f * acc[i][0];
    o0.y = xs + es[1] - 2.f * acc[i][1];
    o0.z = xs + es[2] - 2.f * acc[i][2];
    o0.w = xs + es[3] - 2.f * acc[i][3];
    o1.x = xs + es[4] - 2.f * acc[i][4];
    o1.y = xs + es[5] - 2.f * acc[i][5];
    o1.z = xs + es[6] - 2.f * acc[i][6];
    o1.w = xs + es[7] - 2.f * acc[i][7];
    *(float4*)&dist[(size_t)n * K_CB + k0 + tn * 8] = o0;
    *(float4*)&dist[(size_t)n * K_CB + k0 + tn * 8 + 4] = o1;
  }
}

// ---------------- argmin per row (first-occurrence tie-break) ---------------
__global__ __launch_bounds__(256) void argmin_k(const float* __restrict__ dist, int* __restrict__ idx) {
  int row = blockIdx.x * 4 + (threadIdx.x >> 6);
  int lane = threadIdx.x & 63;
  const float* dr = dist + (size_t)row * K_CB;
  float mv = INFINITY;
  int mi = 0x7fffffff;
#pragma unroll
  for (int t = 0; t < 16; ++t) {
    int k = t * 64 + lane;
    float v = dr[k];
    if (v < mv) { mv = v; mi = k; }
  }
  for (int off = 32; off; off >>= 1) {
    float ov = __shfl_down(mv, off);
    int oi = __shfl_down(mi, off);
    if (ov < mv || (ov == mv && oi < mi)) { mv = ov; mi = oi; }
  }
  if (lane == 0) idx[row] = mi;
}

// ---------------- one-hot scatter + float indices ---------------------------
__global__ __launch_bounds__(256) void scat_k(const int* __restrict__ idx,
                                              float* __restrict__ enc, float* __restrict__ idxf) {
  int n = blockIdx.x * 256 + threadIdx.x;
  int k = idx[n];
  enc[(size_t)n * K_CB + k] = 1.0f;
  idxf[n] = (float)k;
}

// ---------------- counts (LDS-privatized histogram) -------------------------
__global__ __launch_bounds__(256) void counts_k(const int* __restrict__ idx, unsigned* __restrict__ counts) {
  __shared__ unsigned h[K_CB];
  for (int i = threadIdx.x; i < K_CB; i += 256) h[i] = 0;
  __syncthreads();
  for (size_t i = (size_t)blockIdx.x * 256 + threadIdx.x; i < N_ROWS; i += (size_t)gridDim.x * 256)
    atomicAdd(&h[idx[i]], 1u);
  __syncthreads();
  for (int i = threadIdx.x; i < K_CB; i += 256) {
    unsigned v = h[i];
    if (v) atomicAdd(&counts[i], v);
  }
}

// ---------------- exclusive prefix sum over counts --------------------------
__global__ __launch_bounds__(1024) void prefix_k(const unsigned* __restrict__ counts,
                                                 int* __restrict__ start, int* __restrict__ cursor) {
  __shared__ int s[K_CB];
  int t = threadIdx.x;
  int v = (int)counts[t];
  s[t] = v;
  __syncthreads();
  for (int off = 1; off < K_CB; off <<= 1) {
    int x = (t >= off) ? s[t - off] : 0;
    __syncthreads();
    s[t] += x;
    __syncthreads();
  }
  int excl = s[t] - v;
  start[t] = excl;
  cursor[t] = excl;
  if (t == K_CB - 1) start[K_CB] = s[t];
}

// ---------------- scatter row ids into buckets ------------------------------
__global__ __launch_bounds__(256) void scatter_k(const int* __restrict__ idx,
                                                 int* __restrict__ cursor, int* __restrict__ sorted) {
  int n = blockIdx.x * 256 + threadIdx.x;
  int k = idx[n];
  int pos = atomicAdd(&cursor[k], 1);
  sorted[pos] = n;
}

// ---------------- dw segmented gather (no atomics) --------------------------
__global__ __launch_bounds__(256) void dwg_k(const float* __restrict__ flatT,
                                             const int* __restrict__ sorted,
                                             const int* __restrict__ start,
                                             float* __restrict__ dw) {
  int k = blockIdx.x;
  int s = start[k], e = start[k + 1];
  int wave = threadIdx.x >> 6, lane = threadIdx.x & 63;
  float4 acc = {0.f, 0.f, 0.f, 0.f};
  for (int r = s + wave; r < e; r += 4) {
    int n = sorted[r];
    float4 v = *(const float4*)&flatT[(size_t)n * D_DIM + lane * 4];
    acc.x += v.x; acc.y += v.y; acc.z += v.z; acc.w += v.w;
  }
  __shared__ float red[4][D_DIM];
  *(float4*)&red[wave][lane * 4] = acc;
  __syncthreads();
  int tid = threadIdx.x;
  dw[(size_t)k * D_DIM + tid] = red[0][tid] + red[1][tid] + red[2][tid] + red[3][tid];
}

// ---------------- new cluster sizes + perplexity ----------------------------
__global__ __launch_bounds__(1024) void newcs_k(const float* __restrict__ ema_cs,
                                                const unsigned* __restrict__ counts,
                                                float* __restrict__ out_ncs,
                                                float* __restrict__ out_perp) {
  __shared__ float s[1024];
  int k = threadIdx.x;
  float c = (float)counts[k];
  float raw = 0.99f * ema_cs[k] + omd() * c;
  s[k] = raw;
  __syncthreads();
  for (int off = 512; off; off >>= 1) { if (k < off) s[k] += s[k + off]; __syncthreads(); }
  float nsum = s[0];
  __syncthreads();
  out_ncs[k] = (raw + 1e-5f) / (nsum + (float)(1024 * 1e-5)) * nsum;
  float p = c * (1.0f / 131072.0f);
  float t = p * logf(p + 1e-10f);
  s[k] = t;
  __syncthreads();
  for (int off = 512; off; off >>= 1) { if (k < off) s[k] += s[k + off]; __syncthreads(); }
  if (k == 0) out_perp[0] = expf(-s[0]);
}

// ---------------- new ema_w + new embedding ---------------------------------
__global__ __launch_bounds__(256) void newemb_k(const float* __restrict__ ema_w,
                                                const float* __restrict__ dw,
                                                const float* __restrict__ ncs,
                                                float* __restrict__ out_nw,
                                                float* __restrict__ out_ne) {
  int i = blockIdx.x * 256 + threadIdx.x;
  int k = i >> 8;
  float nw = 0.99f * ema_w[i] + omd() * dw[i];
  out_nw[i] = nw;
  out_ne[i] = nw / ncs[k];
}

// ---------------- quantize (gather) + ST output + latent loss ---------------
__global__ __launch_bounds__(256) void quant_k(const float* __restrict__ in,
                                               const int* __restrict__ idx,
                                               const float* __restrict__ ne,
                                               float* __restrict__ qout,
                                               float* __restrict__ lossacc) {
  float lacc = 0.f;
  size_t stride = (size_t)gridDim.x * 256;
  for (size_t i = (size_t)blockIdx.x * 256 + threadIdx.x; i < ND_TOT; i += stride) {
    int d = (int)(i >> 17);
    int n = (int)(i & (N_ROWS - 1));
    float x = in[i];
    float q = ne[(size_t)idx[n] * D_DIM + d];
    float dlt = q - x;
    qout[i] = x + dlt;
    lacc += dlt * dlt;
  }
  for (int off = 32; off; off >>= 1) lacc += __shfl_down(lacc, off);
  __shared__ float w4[4];
  if ((threadIdx.x & 63) == 0) w4[threadIdx.x >> 6] = lacc;
  __syncthreads();
  if (threadIdx.x == 0) atomicAdd(lossacc, w4[0] + w4[1] + w4[2] + w4[3]);
}

__global__ void fin_k(const float* __restrict__ lossacc, float* __restrict__ out_loss) {
  out_loss[0] = 0.25f * lossacc[0] * (1.0f / 33554432.0f);
}

extern "C" void kernel_launch(void* const* d_in, const int* in_sizes, int n_in,
                              void* d_out, int out_size, void* d_ws, size_t ws_size,
                              hipStream_t stream) {
  const float* in     = (const float*)d_in[0];  // [D,B,T]
  const float* emb    = (const float*)d_in[1];  // [K,D]
  const float* ema_cs = (const float*)d_in[2];  // [K]
  const float* ema_w  = (const float*)d_in[3];  // [K,D]

  float* out = (float*)d_out;
  float* out_loss = out;                       // 1
  float* out_q    = out + 1;                   // 33554432
  float* out_perp = out + 33554433;            // 1
  float* out_enc  = out + 33554434;            // 134217728
  float* out_dist = out + 167772162;           // 134217728
  float* out_idx  = out + 301989890;           // 131072
  float* out_ncs  = out + 302120962;           // 1024
  float* out_nw   = out + 302121986;           // 262144
  float* out_ne   = out + 302384130;           // 262144

  char* w = (char*)d_ws;
  unsigned* counts  = (unsigned*)(w);              // 4 KiB
  float*    lossacc = (float*)(w + 4096);          // 4 B
  int*      cursor  = (int*)(w + 8192);            // 4 KiB
  int*      start   = (int*)(w + 12288);           // 1025 ints (8 KiB reserved)
  float*    xsq     = (float*)(w + 20480);         // 512 KiB
  float*    esq     = (float*)(w + 544768);        // 4 KiB
  int*      idx     = (int*)(w + 548864);          // 512 KiB
  int*      sorted  = (int*)(w + 1073152);         // 512 KiB
  float*    dw      = (float*)(w + 1597440);       // 1 MiB

  // flatT scratch lives in out_enc region (134 MB used of 512 MB), consumed
  // by dwg_k BEFORE out_enc is memset for the one-hot output.
  float* flatT = out_enc;

  hipMemsetAsync(d_ws, 0, 8192, stream);  // counts + lossacc

  xsq_k<<<N_ROWS / 256, 256, 0, stream>>>(in, xsq);
  esq_k<<<K_CB / 4, 256, 0, stream>>>(emb, esq);
  tr_k<<<dim3(N_ROWS / 64, D_DIM / 64), 256, 0, stream>>>(in, flatT);
  gemm_dist_k<<<dim3(N_ROWS / 128, K_CB / 128), 256, 0, stream>>>(in, emb, xsq, esq, out_dist);
  argmin_k<<<N_ROWS / 4, 256, 0, stream>>>(out_dist, idx);
  counts_k<<<64, 256, 0, stream>>>(idx, counts);
  prefix_k<<<1, 1024, 0, stream>>>(counts, start, cursor);
  scatter_k<<<N_ROWS / 256, 256, 0, stream>>>(idx, cursor, sorted);
  dwg_k<<<K_CB, 256, 0, stream>>>(flatT, sorted, start, dw);
  hipMemsetAsync(out_enc, 0, NK_TOT * 4, stream);
  scat_k<<<N_ROWS / 256, 256, 0, stream>>>(idx, out_enc, out_idx);
  newcs_k<<<1, 1024, 0, stream>>>(ema_cs, counts, out_ncs, out_perp);
  newemb_k<<<K_CB * D_DIM / 256, 256, 0, stream>>>(ema_w, dw, out_ncs, out_nw, out_ne);
  quant_k<<<2048, 256, 0, stream>>>(in, idx, out_ne, out_q, lossacc);
  fin_k<<<1, 1, 0, stream>>>(lossacc, out_loss);
}

// Round 3
// 1466.142 us; speedup vs baseline: 4.0517x; 1.6396x over previous
//
#include <hip/hip_runtime.h>
#include <cstdint>
#include <cstddef>

#define N_ROWS 131072   // B*T
#define K_CB   1024
#define D_DIM  256
#define ND_TOT 33554432ull   // D*N
#define NK_TOT 134217728ull  // N*K
#define CHUNK  64            // rows of `sorted` per block in dwc_k

static __device__ __forceinline__ float omd() { return (float)(1.0 - 0.99); }

// ---------------- xsq: per-row squared norm of flat (stored [D][N]) ----------
__global__ __launch_bounds__(256) void xsq_k(const float* __restrict__ in, float* __restrict__ xsq) {
  int n = blockIdx.x * 256 + threadIdx.x;
  float s = 0.f;
#pragma unroll 8
  for (int d = 0; d < D_DIM; ++d) {
    float v = in[(size_t)d * N_ROWS + n];
    s += v * v;
  }
  xsq[n] = s;
}

// ---------------- esq: per-code squared norm (emb [K][D] row-major) ----------
__global__ __launch_bounds__(256) void esq_k(const float* __restrict__ emb, float* __restrict__ esq) {
  int k = blockIdx.x * 4 + (threadIdx.x >> 6);
  int lane = threadIdx.x & 63;
  const float* er = emb + (size_t)k * D_DIM;
  float s = 0.f;
#pragma unroll
  for (int t = 0; t < 4; ++t) { float v = er[t * 64 + lane]; s += v * v; }
  for (int off = 32; off; off >>= 1) s += __shfl_down(s, off);
  if (lane == 0) esq[k] = s;
}

// ---------------- tiled transpose: in [D][N] -> flatT [N][D] ----------------
__global__ __launch_bounds__(256) void tr_k(const float* __restrict__ in, float* __restrict__ flatT) {
  __shared__ float tile[64][65];
  int n0 = blockIdx.x * 64, d0 = blockIdx.y * 64;
  int lane = threadIdx.x & 63, grp = threadIdx.x >> 6;
#pragma unroll
  for (int r = 0; r < 16; ++r) {
    int dr = grp * 16 + r;
    tile[dr][lane] = in[(size_t)(d0 + dr) * N_ROWS + n0 + lane];
  }
  __syncthreads();
#pragma unroll
  for (int r = 0; r < 16; ++r) {
    int nr = grp * 16 + r;
    flatT[(size_t)(n0 + nr) * D_DIM + d0 + lane] = tile[lane][nr];
  }
}

// ---------------- fp32 GEMM + distance epilogue -----------------------------
__global__ __launch_bounds__(256) void gemm_dist_k(
    const float* __restrict__ in, const float* __restrict__ emb,
    const float* __restrict__ xsq, const float* __restrict__ esq,
    float* __restrict__ dist) {
  __shared__ float As[8][128];
  __shared__ float Bs[8][132];
  const int tid = threadIdx.x;
  const int n0 = blockIdx.x * 128, k0 = blockIdx.y * 128;
  const int tm = tid >> 4, tn = tid & 15;
  const int a_dk = tid >> 5, a_nn = (tid & 31) << 2;
  const int b_kk = tid >> 1, b_dk = (tid & 1) << 2;
  float acc[8][8] = {};
  for (int d0 = 0; d0 < D_DIM; d0 += 8) {
    float4 av = *(const float4*)&in[(size_t)(d0 + a_dk) * N_ROWS + n0 + a_nn];
    float4 bv = *(const float4*)&emb[(size_t)(k0 + b_kk) * D_DIM + d0 + b_dk];
    __syncthreads();
    *(float4*)&As[a_dk][a_nn] = av;
    Bs[b_dk + 0][b_kk] = bv.x;
    Bs[b_dk + 1][b_kk] = bv.y;
    Bs[b_dk + 2][b_kk] = bv.z;
    Bs[b_dk + 3][b_kk] = bv.w;
    __syncthreads();
#pragma unroll
    for (int dk = 0; dk < 8; ++dk) {
      float a[8], b[8];
      *(float4*)&a[0] = *(const float4*)&As[dk][tm * 8];
      *(float4*)&a[4] = *(const float4*)&As[dk][tm * 8 + 4];
      *(float4*)&b[0] = *(const float4*)&Bs[dk][tn * 8];
      *(float4*)&b[4] = *(const float4*)&Bs[dk][tn * 8 + 4];
#pragma unroll
      for (int i = 0; i < 8; ++i)
#pragma unroll
        for (int j = 0; j < 8; ++j)
          acc[i][j] += a[i] * b[j];
    }
  }
  float es[8];
#pragma unroll
  for (int j = 0; j < 8; ++j) es[j] = esq[k0 + tn * 8 + j];
#pragma unroll
  for (int i = 0; i < 8; ++i) {
    int n = n0 + tm * 8 + i;
    float xs = xsq[n];
    float4 o0, o1;
    o0.x = xs + es[0] - 2.f * acc[i][0];
    o0.y = xs + es[1] - 2.f * acc[i][1];
    o0.z = xs + es[2] - 2.f * acc[i][2];
    o0.w = xs + es[3] - 2.f * acc[i][3];
    o1.x = xs + es[4] - 2.f * acc[i][4];
    o1.y = xs + es[5] - 2.f * acc[i][5];
    o1.z = xs + es[6] - 2.f * acc[i][6];
    o1.w = xs + es[7] - 2.f * acc[i][7];
    *(float4*)&dist[(size_t)n * K_CB + k0 + tn * 8] = o0;
    *(float4*)&dist[(size_t)n * K_CB + k0 + tn * 8 + 4] = o1;
  }
}

// ---------------- argmin per row (first-occurrence tie-break) ---------------
__global__ __launch_bounds__(256) void argmin_k(const float* __restrict__ dist, int* __restrict__ idx) {
  int row = blockIdx.x * 4 + (threadIdx.x >> 6);
  int lane = threadIdx.x & 63;
  const float* dr = dist + (size_t)row * K_CB;
  float mv = INFINITY;
  int mi = 0x7fffffff;
#pragma unroll
  for (int t = 0; t < 16; ++t) {
    int k = t * 64 + lane;
    float v = dr[k];
    if (v < mv) { mv = v; mi = k; }
  }
  for (int off = 32; off; off >>= 1) {
    float ov = __shfl_down(mv, off);
    int oi = __shfl_down(mi, off);
    if (ov < mv || (ov == mv && oi < mi)) { mv = ov; mi = oi; }
  }
  if (lane == 0) idx[row] = mi;
}

// ---------------- one-hot scatter + float indices ---------------------------
__global__ __launch_bounds__(256) void scat_k(const int* __restrict__ idx,
                                              float* __restrict__ enc, float* __restrict__ idxf) {
  int n = blockIdx.x * 256 + threadIdx.x;
  int k = idx[n];
  enc[(size_t)n * K_CB + k] = 1.0f;
  idxf[n] = (float)k;
}

// ---------------- counts (LDS-privatized histogram) -------------------------
__global__ __launch_bounds__(256) void counts_k(const int* __restrict__ idx, unsigned* __restrict__ counts) {
  __shared__ unsigned h[K_CB];
  for (int i = threadIdx.x; i < K_CB; i += 256) h[i] = 0;
  __syncthreads();
  for (size_t i = (size_t)blockIdx.x * 256 + threadIdx.x; i < N_ROWS; i += (size_t)gridDim.x * 256)
    atomicAdd(&h[idx[i]], 1u);
  __syncthreads();
  for (int i = threadIdx.x; i < K_CB; i += 256) {
    unsigned v = h[i];
    if (v) atomicAdd(&counts[i], v);
  }
}

// ---------------- exclusive prefix sum over counts --------------------------
__global__ __launch_bounds__(1024) void prefix_k(const unsigned* __restrict__ counts,
                                                 int* __restrict__ start, int* __restrict__ cursor) {
  __shared__ int s[K_CB];
  int t = threadIdx.x;
  int v = (int)counts[t];
  s[t] = v;
  __syncthreads();
  for (int off = 1; off < K_CB; off <<= 1) {
    int x = (t >= off) ? s[t - off] : 0;
    __syncthreads();
    s[t] += x;
    __syncthreads();
  }
  int excl = s[t] - v;
  start[t] = excl;
  cursor[t] = excl;
  if (t == K_CB - 1) start[K_CB] = s[t];
}

// ---------------- scatter row ids into buckets ------------------------------
__global__ __launch_bounds__(256) void scatter_k(const int* __restrict__ idx,
                                                 int* __restrict__ cursor, int* __restrict__ sorted) {
  int n = blockIdx.x * 256 + threadIdx.x;
  int k = idx[n];
  int pos = atomicAdd(&cursor[k], 1);
  sorted[pos] = n;
}

// ---------------- dw: balanced chunked segmented reduction ------------------
// Grid = N/CHUNK blocks; block b owns sorted[b*CHUNK .. b*CHUNK+CHUNK).
// Thread t = column d. Rows are code-sorted, so per-thread running acc is
// flushed with one atomicAdd at each (wave-uniform) segment boundary.
__global__ __launch_bounds__(256) void dwc_k(const float* __restrict__ flatT,
                                             const int* __restrict__ sorted,
                                             const int* __restrict__ idx,
                                             float* __restrict__ dw) {
  __shared__ int s_n[CHUNK];
  __shared__ int s_k[CHUNK];
  int t = threadIdx.x;
  int r0 = blockIdx.x * CHUNK;
  if (t < CHUNK) {
    int n = sorted[r0 + t];
    s_n[t] = n;
    s_k[t] = idx[n];
  }
  __syncthreads();
  float acc = 0.f;
  for (int rb = 0; rb < CHUNK; rb += 8) {
    float v[8];
#pragma unroll
    for (int i = 0; i < 8; ++i)
      v[i] = flatT[(size_t)s_n[rb + i] * D_DIM + t];
#pragma unroll
    for (int i = 0; i < 8; ++i) {
      int r = rb + i;
      acc += v[i];
      if (r == CHUNK - 1 || s_k[r + 1] != s_k[r]) {
        atomicAdd(&dw[(size_t)s_k[r] * D_DIM + t], acc);
        acc = 0.f;
      }
    }
  }
}

// ---------------- new cluster sizes + perplexity ----------------------------
__global__ __launch_bounds__(1024) void newcs_k(const float* __restrict__ ema_cs,
                                                const unsigned* __restrict__ counts,
                                                float* __restrict__ out_ncs,
                                                float* __restrict__ out_perp) {
  __shared__ float s[1024];
  int k = threadIdx.x;
  float c = (float)counts[k];
  float raw = 0.99f * ema_cs[k] + omd() * c;
  s[k] = raw;
  __syncthreads();
  for (int off = 512; off; off >>= 1) { if (k < off) s[k] += s[k + off]; __syncthreads(); }
  float nsum = s[0];
  __syncthreads();
  out_ncs[k] = (raw + 1e-5f) / (nsum + (float)(1024 * 1e-5)) * nsum;
  float p = c * (1.0f / 131072.0f);
  float t = p * logf(p + 1e-10f);
  s[k] = t;
  __syncthreads();
  for (int off = 512; off; off >>= 1) { if (k < off) s[k] += s[k + off]; __syncthreads(); }
  if (k == 0) out_perp[0] = expf(-s[0]);
}

// ---------------- new ema_w + new embedding ---------------------------------
__global__ __launch_bounds__(256) void newemb_k(const float* __restrict__ ema_w,
                                                const float* __restrict__ dw,
                                                const float* __restrict__ ncs,
                                                float* __restrict__ out_nw,
                                                float* __restrict__ out_ne) {
  int i = blockIdx.x * 256 + threadIdx.x;
  int k = i >> 8;
  float nw = 0.99f * ema_w[i] + omd() * dw[i];
  out_nw[i] = nw;
  out_ne[i] = nw / ncs[k];
}

// ---------------- quantize (gather) + ST output + latent loss ---------------
__global__ __launch_bounds__(256) void quant_k(const float* __restrict__ in,
                                               const int* __restrict__ idx,
                                               const float* __restrict__ ne,
                                               float* __restrict__ qout,
                                               float* __restrict__ lossacc) {
  float lacc = 0.f;
  size_t stride = (size_t)gridDim.x * 256;
  for (size_t i = (size_t)blockIdx.x * 256 + threadIdx.x; i < ND_TOT; i += stride) {
    int d = (int)(i >> 17);
    int n = (int)(i & (N_ROWS - 1));
    float x = in[i];
    float q = ne[(size_t)idx[n] * D_DIM + d];
    float dlt = q - x;
    qout[i] = x + dlt;
    lacc += dlt * dlt;
  }
  for (int off = 32; off; off >>= 1) lacc += __shfl_down(lacc, off);
  __shared__ float w4[4];
  if ((threadIdx.x & 63) == 0) w4[threadIdx.x >> 6] = lacc;
  __syncthreads();
  if (threadIdx.x == 0) atomicAdd(lossacc, w4[0] + w4[1] + w4[2] + w4[3]);
}

__global__ void fin_k(const float* __restrict__ lossacc, float* __restrict__ out_loss) {
  out_loss[0] = 0.25f * lossacc[0] * (1.0f / 33554432.0f);
}

extern "C" void kernel_launch(void* const* d_in, const int* in_sizes, int n_in,
                              void* d_out, int out_size, void* d_ws, size_t ws_size,
                              hipStream_t stream) {
  const float* in     = (const float*)d_in[0];  // [D,B,T]
  const float* emb    = (const float*)d_in[1];  // [K,D]
  const float* ema_cs = (const float*)d_in[2];  // [K]
  const float* ema_w  = (const float*)d_in[3];  // [K,D]

  float* out = (float*)d_out;
  float* out_loss = out;                       // 1
  float* out_q    = out + 1;                   // 33554432
  float* out_perp = out + 33554433;            // 1
  float* out_enc  = out + 33554434;            // 134217728
  float* out_dist = out + 167772162;           // 134217728
  float* out_idx  = out + 301989890;           // 131072
  float* out_ncs  = out + 302120962;           // 1024
  float* out_nw   = out + 302121986;           // 262144
  float* out_ne   = out + 302384130;           // 262144

  char* w = (char*)d_ws;
  unsigned* counts  = (unsigned*)(w);              // 4 KiB
  float*    lossacc = (float*)(w + 4096);          // 4 B
  int*      cursor  = (int*)(w + 8192);            // 4 KiB
  int*      start   = (int*)(w + 12288);           // 1025 ints (8 KiB reserved)
  float*    xsq     = (float*)(w + 20480);         // 512 KiB
  float*    esq     = (float*)(w + 544768);        // 4 KiB
  int*      idx     = (int*)(w + 548864);          // 512 KiB
  int*      sorted  = (int*)(w + 1073152);         // 512 KiB
  float*    dw      = (float*)(w + 1597440);       // 1 MiB

  // flatT scratch lives in out_enc region (134 MB used of 512 MB), consumed
  // by dwc_k BEFORE out_enc is memset for the one-hot output.
  float* flatT = out_enc;

  hipMemsetAsync(d_ws, 0, 8192, stream);           // counts + lossacc
  hipMemsetAsync(dw, 0, K_CB * D_DIM * 4, stream); // dw is atomic-accumulated now

  xsq_k<<<N_ROWS / 256, 256, 0, stream>>>(in, xsq);
  esq_k<<<K_CB / 4, 256, 0, stream>>>(emb, esq);
  tr_k<<<dim3(N_ROWS / 64, D_DIM / 64), 256, 0, stream>>>(in, flatT);
  gemm_dist_k<<<dim3(N_ROWS / 128, K_CB / 128), 256, 0, stream>>>(in, emb, xsq, esq, out_dist);
  argmin_k<<<N_ROWS / 4, 256, 0, stream>>>(out_dist, idx);
  counts_k<<<64, 256, 0, stream>>>(idx, counts);
  prefix_k<<<1, 1024, 0, stream>>>(counts, start, cursor);
  scatter_k<<<N_ROWS / 256, 256, 0, stream>>>(idx, cursor, sorted);
  dwc_k<<<N_ROWS / CHUNK, 256, 0, stream>>>(flatT, sorted, idx, dw);
  hipMemsetAsync(out_enc, 0, NK_TOT * 4, stream);
  scat_k<<<N_ROWS / 256, 256, 0, stream>>>(idx, out_enc, out_idx);
  newcs_k<<<1, 1024, 0, stream>>>(ema_cs, counts, out_ncs, out_perp);
  newemb_k<<<K_CB * D_DIM / 256, 256, 0, stream>>>(ema_w, dw, out_ncs, out_nw, out_ne);
  quant_k<<<2048, 256, 0, stream>>>(in, idx, out_ne, out_q, lossacc);
  fin_k<<<1, 1, 0, stream>>>(lossacc, out_loss);
}